// Round 5
// baseline (241.339 us; speedup 1.0000x reference)
//
#include <hip/hip_runtime.h>
#include <stdint.h>

// LinearAttention on MI355X — round 9: fix round-8 register spills.
// Same pipelined fused k13 (counted vmcnt, merged K/V k-loop), but:
//  - no persistent ctx accumulator: GEMM3 -> fresh accG -> atomicAdd per chunk
//    (max live set = accK+accV+rsum = 144 regs, round-7-proven spill-free)
//  - amdgpu_waves_per_eu(2,2): allocator knows 2 waves/EU run -> 256-reg budget
//
// final_b = N_b · x_b + bias;  N_b = (W_out ⊙ ctx_b) · W_q;
// ctx_b[h] = (1/rowsum) · exp(K)·V^T  (exp without max-subtraction: K~N(0,0.64), safe).
//
// ws layout (bytes):
//   xbT    bf16 [8][4096][256]  @ 0          (16,777,216)
//   wkvb   bf16 [1024][256]     @ 16777216   (   524,288)
//   woutb  bf16 [256][512]      @ 17301504   (   262,144)
//   wqT    bf16 [256][512]      @ 17563648   (   262,144)
//   ctx    f32  [32][128][128]  @ 17825792   ( 2,097,152)  atomic accum
//   rowsum f32  [8][512]        @ 19922944   (    16,384)  atomic accum
//   ctxb   bf16 [32][128][128]  @ 19939328   ( 1,048,576)
//   Mb     bf16 [8][256][512]   @ 20987904   ( 2,097,152)
//   Nb     bf16 [8][256][256]   @ 23085056   ( 1,048,576)
// total 24,133,632 B

using frag8 = __attribute__((ext_vector_type(8))) short;   // 8 x bf16
using f32x4 = __attribute__((ext_vector_type(4))) float;

__device__ __forceinline__ unsigned short f2bf(float f) {
    union { float f; unsigned int u; } c; c.f = f;
    unsigned int u = c.u;
    return (unsigned short)((u + 0x7FFFu + ((u >> 16) & 1u)) >> 16);
}

__device__ __forceinline__ void gl_lds16(const void* g, void* l) {
    __builtin_amdgcn_global_load_lds(
        (const __attribute__((address_space(1))) unsigned int*)g,
        (__attribute__((address_space(3))) unsigned int*)l, 16, 0, 0);
}

// ------- k0_prep: xbT transpose (blk<2048) + weight prep (blk>=2048) -------
__global__ __launch_bounds__(256) void k0_prep(
    const float* __restrict__ x, const float* __restrict__ w_qkv,
    const float* __restrict__ w_out,
    unsigned short* __restrict__ xbT, unsigned short* __restrict__ wkvb,
    unsigned short* __restrict__ woutb, unsigned short* __restrict__ wqT)
{
    __shared__ float T[64][65];
    const int tid = threadIdx.x;
    const int blk0 = blockIdx.x;
    if (blk0 < 2048) {               // xbT[b][n][c] = bf16(x[b][c][n])
        const int n0 = (blk0 & 63) * 64, c0 = ((blk0 >> 6) & 3) * 64, b = blk0 >> 8;
        const float* xb = x + (size_t)b * 1048576;
        const int cr = tid >> 4, nc = (tid & 15) * 4;
        #pragma unroll
        for (int p = 0; p < 4; ++p) {
            float4 v = *(const float4*)(xb + (size_t)(c0 + cr + p * 16) * 4096 + n0 + nc);
            T[cr + p * 16][nc + 0] = v.x; T[cr + p * 16][nc + 1] = v.y;
            T[cr + p * 16][nc + 2] = v.z; T[cr + p * 16][nc + 3] = v.w;
        }
        __syncthreads();
        const int n = tid >> 2, cc = (tid & 3) * 16;
        unsigned short* dst = xbT + (size_t)b * 1048576 + (size_t)(n0 + n) * 256 + c0 + cc;
        #pragma unroll
        for (int g = 0; g < 4; ++g) {
            ushort4 o;
            o.x = f2bf(T[cc + g * 4 + 0][n]);
            o.y = f2bf(T[cc + g * 4 + 1][n]);
            o.z = f2bf(T[cc + g * 4 + 2][n]);
            o.w = f2bf(T[cc + g * 4 + 3][n]);
            *(ushort4*)(dst + g * 4) = o;
        }
        return;
    }
    const int blk = blk0 - 2048;
    if (blk < 256) {                 // wkvb: w_qkv rows 512..1536 -> bf16
        const int idx = (blk * 256 + tid) * 4;
        float4 v = *(const float4*)(w_qkv + 512 * 256 + idx);
        ushort4 o;
        o.x = f2bf(v.x); o.y = f2bf(v.y); o.z = f2bf(v.z); o.w = f2bf(v.w);
        *(ushort4*)(wkvb + idx) = o;
    } else if (blk < 384) {          // woutb: w_out -> bf16
        const int idx = ((blk - 256) * 256 + tid) * 4;
        float4 v = *(const float4*)(w_out + idx);
        ushort4 o;
        o.x = f2bf(v.x); o.y = f2bf(v.y); o.z = f2bf(v.z); o.w = f2bf(v.w);
        *(ushort4*)(woutb + idx) = o;
    } else {                         // wqT[c][j] = bf16(w_qkv[j][c]), j<512
        const int t = blk - 384;     // 32 tiles: 8 j-tiles x 4 c-tiles
        const int j0 = (t >> 2) * 64, c0 = (t & 3) * 64;
        const int r = tid >> 4, cc = (tid & 15) * 4;
        #pragma unroll
        for (int p = 0; p < 4; ++p) {
            float4 v = *(const float4*)(w_qkv + (j0 + r + p * 16) * 256 + c0 + cc);
            T[r + p * 16][cc + 0] = v.x; T[r + p * 16][cc + 1] = v.y;
            T[r + p * 16][cc + 2] = v.z; T[r + p * 16][cc + 3] = v.w;
        }
        __syncthreads();
        const int c = tid >> 2, jj = (tid & 3) * 16;
        #pragma unroll
        for (int g = 0; g < 4; ++g) {
            ushort4 o;
            o.x = f2bf(T[jj + g * 4 + 0][c]);
            o.y = f2bf(T[jj + g * 4 + 1][c]);
            o.z = f2bf(T[jj + g * 4 + 2][c]);
            o.w = f2bf(T[jj + g * 4 + 3][c]);
            *(ushort4*)(wqT + (c0 + c) * 512 + j0 + jj + g * 4) = o;
        }
    }
}

// -------- MFMA gemm_bt: C[m][n] = sum_k A[m][k] * B[n][k]  (bf16 in) -------
// 128x128 block tile, BK=32, 4 waves (each 64x64), 16x16x32 bf16 MFMA.
// Staging uses XOR involution swizzle (source-side + read-side).
// MODE 0: C bf16, z-strided (k5: N).
// MODE 1: C f32 + bias[row] (k6: out).
// MODE 3: k4 M — A=woutb col-block h, B=ctxb[bh], C=Mb col-block h, bf16.
template<int MODE>
__global__ __launch_bounds__(256) void mfma_bt(
    const unsigned short* __restrict__ A0, int lda,
    const unsigned short* __restrict__ B0, int ldb,
    void* __restrict__ C0, int ldc,
    const float* __restrict__ bias, int Kp,
    unsigned long long sAz, unsigned long long sBz, unsigned long long sCz)
{
    __shared__ unsigned short As[128 * 32];
    __shared__ unsigned short Bs[128 * 32];
    const int tid  = threadIdx.x;
    const int w    = tid >> 6, lane = tid & 63;
    const int quad = lane >> 4, l16 = lane & 15;
    const int wm = (w >> 1) * 64, wn = (w & 1) * 64;
    const int z = blockIdx.z;

    const unsigned short* A;
    const unsigned short* B;
    int m0, n0;
    if constexpr (MODE == 3) {
        m0 = blockIdx.y * 128; n0 = 0;
        A = A0 + (unsigned long long)(z & 3) * 128ull + (unsigned long long)m0 * lda;
        B = B0 + (unsigned long long)z * 16384ull;
    } else {
        m0 = blockIdx.y * 128; n0 = blockIdx.x * 128;
        A = A0 + sAz * z + (unsigned long long)m0 * lda;
        B = B0 + sBz * z + (unsigned long long)n0 * ldb;
    }

    const int c0 = w * 128 + lane, c1 = c0 + 64;
    const int r0 = c0 >> 2, g0 = ((c0 & 3) ^ ((r0 >> 1) & 3)) * 8;
    const int r1 = c1 >> 2, g1 = ((c1 & 3) ^ ((r1 >> 1) & 3)) * 8;
    const unsigned short* gA0 = A + (unsigned long long)r0 * lda + g0;
    const unsigned short* gA1 = A + (unsigned long long)r1 * lda + g1;
    const unsigned short* gB0 = B + (unsigned long long)r0 * ldb + g0;
    const unsigned short* gB1 = B + (unsigned long long)r1 * ldb + g1;
    unsigned short* lA0 = As + w * 1024;
    unsigned short* lA1 = As + w * 1024 + 512;
    unsigned short* lB0 = Bs + w * 1024;
    unsigned short* lB1 = Bs + w * 1024 + 512;

    f32x4 acc[4][4] = {};

    for (int k0 = 0; k0 < Kp; k0 += 32) {
        gl_lds16(gA0 + k0, lA0);
        gl_lds16(gA1 + k0, lA1);
        gl_lds16(gB0 + k0, lB0);
        gl_lds16(gB1 + k0, lB1);
        __syncthreads();
        frag8 a[4], b[4];
        #pragma unroll
        for (int t = 0; t < 4; ++t) {
            const int ra = wm + t * 16 + l16;
            const int rb = wn + t * 16 + l16;
            a[t] = *(const frag8*)(As + ra * 32 + ((quad ^ ((ra >> 1) & 3)) << 3));
            b[t] = *(const frag8*)(Bs + rb * 32 + ((quad ^ ((rb >> 1) & 3)) << 3));
        }
        #pragma unroll
        for (int mt = 0; mt < 4; ++mt)
            #pragma unroll
            for (int nt = 0; nt < 4; ++nt)
                acc[mt][nt] = __builtin_amdgcn_mfma_f32_16x16x32_bf16(
                    a[mt], b[nt], acc[mt][nt], 0, 0, 0);
        __syncthreads();
    }

    // epilogue: C/D mapping col = lane&15, row = quad*4 + reg  [m91-verified]
    if constexpr (MODE == 0 || MODE == 3) {
        unsigned short* C;
        if constexpr (MODE == 0)
            C = (unsigned short*)C0 + sCz * z + (unsigned long long)m0 * ldc + n0;
        else
            C = (unsigned short*)C0 + (unsigned long long)(z >> 2) * 131072ull
              + (unsigned long long)(z & 3) * 128ull + (unsigned long long)m0 * ldc;
        #pragma unroll
        for (int mt = 0; mt < 4; ++mt) {
            const int row = wm + mt * 16 + quad * 4;
            #pragma unroll
            for (int nt = 0; nt < 4; ++nt) {
                const int col = wn + nt * 16 + l16;
                #pragma unroll
                for (int r = 0; r < 4; ++r)
                    C[(unsigned long long)(row + r) * ldc + col] = f2bf(acc[mt][nt][r]);
            }
        }
    } else {
        float* C = (float*)C0 + sCz * z + (unsigned long long)m0 * ldc + n0;
        const float* bp = bias + m0;
        #pragma unroll
        for (int mt = 0; mt < 4; ++mt) {
            const int row = wm + mt * 16 + quad * 4;
            #pragma unroll
            for (int nt = 0; nt < 4; ++nt) {
                const int col = wn + nt * 16 + l16;
                #pragma unroll
                for (int r = 0; r < 4; ++r)
                    C[(unsigned long long)(row + r) * ldc + col] = acc[mt][nt][r] + bp[row + r];
            }
        }
    }
}

// ------------- k13_ctx: fused kv-GEMM + exp + context, pipelined -----------
// grid (16 slices, 4 heads, 8 batches) = 512 blocks, 2 blocks/CU, one round.
__global__ __launch_bounds__(256)
__attribute__((amdgpu_waves_per_eu(2, 2)))
void k13_ctx(
    const unsigned short* __restrict__ wkvb,
    const unsigned short* __restrict__ xbT,
    float* __restrict__ ctx, float* __restrict__ rowsum)
{
    // 64 KB overlay: [0,24576) staging dbuf (Wk|Wv|X x2), later Kt[0,16384) Vt[16384,32768)
    __shared__ unsigned short smem[32768];
    const int tid  = threadIdx.x;
    const int w    = tid >> 6, lane = tid & 63;
    const int quad = lane >> 4, l16 = lane & 15;
    const int wm = (w >> 1) * 64, wn = (w & 1) * 64;
    const int h = blockIdx.y, b = blockIdx.z;

    const unsigned short* Wk = wkvb + (size_t)(h * 128) * 256;
    const unsigned short* Wv = wkvb + (size_t)(512 + h * 128) * 256;
    const unsigned short* Xb = xbT + (size_t)b * 1048576 + (size_t)blockIdx.x * 65536;

    // staging chunks: per wave, per tile, chunks [w*128, w*128+128); two 16B ops each
    const int c0 = w * 128 + lane, c1 = c0 + 64;
    const int r0 = c0 >> 2, s0 = ((c0 & 3) ^ ((r0 >> 1) & 3)) * 8;
    const int r1 = c1 >> 2, s1 = ((c1 & 3) ^ ((r1 >> 1) & 3)) * 8;
    const unsigned short* gWk0 = Wk + (size_t)r0 * 256 + s0;
    const unsigned short* gWk1 = Wk + (size_t)r1 * 256 + s1;
    const unsigned short* gWv0 = Wv + (size_t)r0 * 256 + s0;
    const unsigned short* gWv1 = Wv + (size_t)r1 * 256 + s1;
    const int ldsw = w * 1024;

    unsigned short* Kt = smem;
    unsigned short* Vt = smem + 16384;

    float rsum[4][4] = {};
    float* cp = ctx + (size_t)(b * 4 + h) * 16384ull;

    #pragma unroll 1
    for (int ch = 0; ch < 2; ++ch) {
        const unsigned short* gX0 = Xb + (size_t)ch * 32768 + (size_t)r0 * 256 + s0;
        const unsigned short* gX1 = Xb + (size_t)ch * 32768 + (size_t)r1 * 256 + s1;

        f32x4 accK[4][4] = {};
        f32x4 accV[4][4] = {};

#define STAGE(T, BSEL) do {                                              \
        unsigned short* bp_ = smem + (BSEL) * 12288 + ldsw;              \
        gl_lds16(gWk0 + (T) * 32, bp_);                                  \
        gl_lds16(gWk1 + (T) * 32, bp_ + 512);                            \
        gl_lds16(gWv0 + (T) * 32, bp_ + 4096);                           \
        gl_lds16(gWv1 + (T) * 32, bp_ + 4096 + 512);                     \
        gl_lds16(gX0  + (T) * 32, bp_ + 8192);                           \
        gl_lds16(gX1  + (T) * 32, bp_ + 8192 + 512);                     \
    } while (0)

        STAGE(0, 0);
        #pragma unroll
        for (int t = 0; t < 8; ++t) {
            if (t < 7) {
                STAGE(t + 1, (t + 1) & 1);
                asm volatile("s_waitcnt vmcnt(6)" ::: "memory");
            } else {
                asm volatile("s_waitcnt vmcnt(0)" ::: "memory");
            }
            __builtin_amdgcn_sched_barrier(0);
            __builtin_amdgcn_s_barrier();
            __builtin_amdgcn_sched_barrier(0);
            const unsigned short* bp = smem + (t & 1) * 12288;
            frag8 fb[4], fa[4];
            #pragma unroll
            for (int tt = 0; tt < 4; ++tt) {
                const int rb = wn + tt * 16 + l16;
                fb[tt] = *(const frag8*)(bp + 8192 + rb * 32 + ((quad ^ ((rb >> 1) & 3)) << 3));
            }
            #pragma unroll
            for (int tt = 0; tt < 4; ++tt) {
                const int ra = wm + tt * 16 + l16;
                fa[tt] = *(const frag8*)(bp + ra * 32 + ((quad ^ ((ra >> 1) & 3)) << 3));
            }
            #pragma unroll
            for (int mt = 0; mt < 4; ++mt)
                #pragma unroll
                for (int nt = 0; nt < 4; ++nt)
                    accK[mt][nt] = __builtin_amdgcn_mfma_f32_16x16x32_bf16(
                        fa[mt], fb[nt], accK[mt][nt], 0, 0, 0);
            #pragma unroll
            for (int tt = 0; tt < 4; ++tt) {
                const int ra = wm + tt * 16 + l16;
                fa[tt] = *(const frag8*)(bp + 4096 + ra * 32 + ((quad ^ ((ra >> 1) & 3)) << 3));
            }
            #pragma unroll
            for (int mt = 0; mt < 4; ++mt)
                #pragma unroll
                for (int nt = 0; nt < 4; ++nt)
                    accV[mt][nt] = __builtin_amdgcn_mfma_f32_16x16x32_bf16(
                        fa[mt], fb[nt], accV[mt][nt], 0, 0, 0);
            __builtin_amdgcn_sched_barrier(0);
            __builtin_amdgcn_s_barrier();
        }
#undef STAGE

        // exp(K) -> Kt, V -> Vt (XOR-swizzled: idx ^ ((row&7)<<3)); overlay is safe:
        // staging reads all consumed before the loop-end barrier.
        #pragma unroll
        for (int mt = 0; mt < 4; ++mt) {
            const int row = wm + mt * 16 + quad * 4;
            #pragma unroll
            for (int nt = 0; nt < 4; ++nt) {
                const int col = wn + nt * 16 + l16;
                #pragma unroll
                for (int r = 0; r < 4; ++r) {
                    float e = __expf(accK[mt][nt][r]);
                    rsum[mt][r] += e;
                    Kt[((row + r) * 128 + col) ^ (((row + r) & 7) << 3)] = f2bf(e);
                    Vt[((row + r) * 128 + col) ^ (((row + r) & 7) << 3)] = f2bf(accV[mt][nt][r]);
                }
            }
        }
        asm volatile("s_waitcnt lgkmcnt(0)" ::: "memory");
        __builtin_amdgcn_s_barrier();

        // GEMM3: accG[d][e] = sum_n Kt[d][n] * Vt[e][n]  (fresh acc, reuses accK/V regs)
        f32x4 accG[4][4] = {};
        #pragma unroll
        for (int kk = 0; kk < 4; ++kk) {
            frag8 a[4], bb[4];
            #pragma unroll
            for (int t = 0; t < 4; ++t) {
                const int ra = wm + t * 16 + l16;
                const int rb = wn + t * 16 + l16;
                a[t]  = *(const frag8*)(Kt + ((ra * 128 + kk * 32 + quad * 8) ^ ((ra & 7) << 3)));
                bb[t] = *(const frag8*)(Vt + ((rb * 128 + kk * 32 + quad * 8) ^ ((rb & 7) << 3)));
            }
            #pragma unroll
            for (int mt = 0; mt < 4; ++mt)
                #pragma unroll
                for (int nt = 0; nt < 4; ++nt)
                    accG[mt][nt] = __builtin_amdgcn_mfma_f32_16x16x32_bf16(
                        a[mt], bb[nt], accG[mt][nt], 0, 0, 0);
        }
        // atomic accumulate this chunk's context (ctx is L2-resident, 2 MB)
        #pragma unroll
        for (int mt = 0; mt < 4; ++mt) {
            const int row = wm + mt * 16 + quad * 4;
            #pragma unroll
            for (int nt = 0; nt < 4; ++nt) {
                const int col = wn + nt * 16 + l16;
                #pragma unroll
                for (int r = 0; r < 4; ++r)
                    atomicAdd(cp + (row + r) * 128 + col, accG[mt][nt][r]);
            }
        }
        __builtin_amdgcn_s_barrier();   // GEMM3 reads done before next chunk re-stages
    }

    // epilogue: per-row exp-sums
    float* rs = rowsum + b * 512 + h * 128;
    #pragma unroll
    for (int mt = 0; mt < 4; ++mt) {
        const int row = wm + mt * 16 + quad * 4;
        #pragma unroll
        for (int r = 0; r < 4; ++r) {
            float v = rsum[mt][r];
            v += __shfl_xor(v, 1, 64);
            v += __shfl_xor(v, 2, 64);
            v += __shfl_xor(v, 4, 64);
            v += __shfl_xor(v, 8, 64);
            if (l16 == 0) atomicAdd(rs + row + r, v);
        }
    }
}

// ---- k3_scale: ctxb[bh][d][e] = bf16( ctx[bh][d][e] / rowsum[bh*128+d] ) --
__global__ __launch_bounds__(256) void k3_scale(
    const float* __restrict__ ctx, const float* __restrict__ rowsum,
    unsigned short* __restrict__ ctxb)
{
    const int idx = (blockIdx.x * 256 + threadIdx.x) * 4;   // element index
    const float inv = 1.0f / rowsum[idx >> 7];              // row = bh*128+d
    float4 t = *(const float4*)(ctx + idx);
    ushort4 o;
    o.x = f2bf(t.x * inv); o.y = f2bf(t.y * inv);
    o.z = f2bf(t.z * inv); o.w = f2bf(t.w * inv);
    *(ushort4*)(ctxb + idx) = o;
}

extern "C" void kernel_launch(void* const* d_in, const int* in_sizes, int n_in,
                              void* d_out, int out_size, void* d_ws, size_t ws_size,
                              hipStream_t stream) {
    (void)in_sizes; (void)n_in; (void)out_size; (void)ws_size;
    const float* x     = (const float*)d_in[0];  // f32 [8,256,64,64]
    const float* w_qkv = (const float*)d_in[1];  // f32 [1536,256]
    const float* w_out = (const float*)d_in[2];  // f32 [256,512]
    const float* b_out = (const float*)d_in[3];  // f32 [256]
    float* out = (float*)d_out;                  // f32 [8,256,64,64]

    char* ws = (char*)d_ws;
    unsigned short* xbT    = (unsigned short*)ws;                 // 16,777,216
    unsigned short* wkvb   = (unsigned short*)(ws + 16777216);    //    524,288
    unsigned short* woutb  = (unsigned short*)(ws + 17301504);    //    262,144
    unsigned short* wqT    = (unsigned short*)(ws + 17563648);    //    262,144
    float*          ctx    = (float*)(ws + 17825792);             //  2,097,152
    float*          rowsum = (float*)(ws + 19922944);             //     16,384
    unsigned short* ctxb   = (unsigned short*)(ws + 19939328);    //  1,048,576
    unsigned short* Mb     = (unsigned short*)(ws + 20987904);    //  2,097,152
    unsigned short* Nb     = (unsigned short*)(ws + 23085056);    //  1,048,576

    // zero atomic accumulators (ctx + rowsum, adjacent): 2,113,536 B
    hipMemsetAsync(ws + 17825792, 0, 2097152 + 16384, stream);

    k0_prep<<<dim3(2464), 256, 0, stream>>>(x, w_qkv, w_out, xbT, wkvb, woutb, wqT);
    // fused kv + exp + context (pipelined)
    k13_ctx<<<dim3(16, 4, 8), 256, 0, stream>>>(wkvb, xbT, ctx, rowsum);
    k3_scale<<<dim3(512), 256, 0, stream>>>(ctx, rowsum, ctxb);
    // k4: Mb[b][o][h*128+d] = sum_e woutb[o][h*128+e] * ctxb[bh][d][e]
    mfma_bt<3><<<dim3(1, 2, 32), 256, 0, stream>>>(
        woutb, 512, ctxb, 128, Mb, 512, nullptr, 128,
        0ull, 0ull, 0ull);
    // k5: Nb[b][o][c] = sum_j Mb[b][o][j] * wqT[c][j]
    mfma_bt<0><<<dim3(2, 2, 8), 256, 0, stream>>>(
        Mb, 512, wqT, 512, Nb, 256, nullptr, 512,
        131072ull, 0ull, 65536ull);
    // k6: out[b,o,n] = sum_c Nb[b,o,c] * xbT[b,n,c] + b_out[o]
    mfma_bt<1><<<dim3(32, 2, 8), 256, 0, stream>>>(
        Nb, 256, xbT, 256, out, 4096, b_out, 256,
        65536ull, 1048576ull, 1048576ull);
}

// Round 6
// 198.055 us; speedup vs baseline: 1.2185x; 1.2185x over previous
//
#include <hip/hip_runtime.h>
#include <stdint.h>

// LinearAttention on MI355X — round 10: back to the unfused round-1 structure,
// with pipelined GEMMs.
//  - k1p: W-resident kv producer. Wk/Wv tile (64KB) stays in LDS; X streamed
//    via 2-deep dbuf with counted vmcnt(2) (drain only at subtile epilogues).
//    exp(K) + rowsum epilogue identical to the proven round-1 MODE4.
//  - mfma_bt: double-buffered 2-phase (stage t+2 while computing t, vmcnt(4)),
//    staging XOR-involution swizzle kept. MODE2 = single-pass ctx atomics.
//
// final_b = N_b · x_b + bias;  N_b = (W_out ⊙ ctx_b) · W_q;
// ctx_b[h] = (1/rowsum) · exp(K)·V^T  (exp w/o max-subtraction: K~N(0,0.64), safe).
//
// ws layout (bytes):
//   xbT    bf16 [8][4096][256]  @ 0          (16,777,216)
//   wkvb   bf16 [1024][256]     @ 16777216   (   524,288)
//   woutb  bf16 [256][512]      @ 17301504   (   262,144)
//   wqT    bf16 [256][512]      @ 17563648   (   262,144)
//   ctx    f32  [32][128][128]  @ 17825792   ( 2,097,152)  atomic accum
//   rowsum f32  [8][512]        @ 19922944   (    16,384)  atomic accum
//   ctxb   bf16 [32][128][128]  @ 19939328   ( 1,048,576)
//   Mb     bf16 [8][256][512]   @ 20987904   ( 2,097,152)
//   Nb     bf16 [8][256][256]   @ 23085056   ( 1,048,576)
//   kv     bf16 [8][1024][4096] @ 24133632   (67,108,864)  K part = exp(K)
// total 91,242,496 B

using frag8 = __attribute__((ext_vector_type(8))) short;   // 8 x bf16
using f32x4 = __attribute__((ext_vector_type(4))) float;

__device__ __forceinline__ unsigned short f2bf(float f) {
    union { float f; unsigned int u; } c; c.f = f;
    unsigned int u = c.u;
    return (unsigned short)((u + 0x7FFFu + ((u >> 16) & 1u)) >> 16);
}

__device__ __forceinline__ void gl_lds16(const void* g, void* l) {
    __builtin_amdgcn_global_load_lds(
        (const __attribute__((address_space(1))) unsigned int*)g,
        (__attribute__((address_space(3))) unsigned int*)l, 16, 0, 0);
}

// ------- k0_prep: xbT transpose (blk<2048) + weight prep (blk>=2048) -------
__global__ __launch_bounds__(256) void k0_prep(
    const float* __restrict__ x, const float* __restrict__ w_qkv,
    const float* __restrict__ w_out,
    unsigned short* __restrict__ xbT, unsigned short* __restrict__ wkvb,
    unsigned short* __restrict__ woutb, unsigned short* __restrict__ wqT)
{
    __shared__ float T[64][65];
    const int tid = threadIdx.x;
    const int blk0 = blockIdx.x;
    if (blk0 < 2048) {               // xbT[b][n][c] = bf16(x[b][c][n])
        const int n0 = (blk0 & 63) * 64, c0 = ((blk0 >> 6) & 3) * 64, b = blk0 >> 8;
        const float* xb = x + (size_t)b * 1048576;
        const int cr = tid >> 4, nc = (tid & 15) * 4;
        #pragma unroll
        for (int p = 0; p < 4; ++p) {
            float4 v = *(const float4*)(xb + (size_t)(c0 + cr + p * 16) * 4096 + n0 + nc);
            T[cr + p * 16][nc + 0] = v.x; T[cr + p * 16][nc + 1] = v.y;
            T[cr + p * 16][nc + 2] = v.z; T[cr + p * 16][nc + 3] = v.w;
        }
        __syncthreads();
        const int n = tid >> 2, cc = (tid & 3) * 16;
        unsigned short* dst = xbT + (size_t)b * 1048576 + (size_t)(n0 + n) * 256 + c0 + cc;
        #pragma unroll
        for (int g = 0; g < 4; ++g) {
            ushort4 o;
            o.x = f2bf(T[cc + g * 4 + 0][n]);
            o.y = f2bf(T[cc + g * 4 + 1][n]);
            o.z = f2bf(T[cc + g * 4 + 2][n]);
            o.w = f2bf(T[cc + g * 4 + 3][n]);
            *(ushort4*)(dst + g * 4) = o;
        }
        return;
    }
    const int blk = blk0 - 2048;
    if (blk < 256) {                 // wkvb: w_qkv rows 512..1536 -> bf16
        const int idx = (blk * 256 + tid) * 4;
        float4 v = *(const float4*)(w_qkv + 512 * 256 + idx);
        ushort4 o;
        o.x = f2bf(v.x); o.y = f2bf(v.y); o.z = f2bf(v.z); o.w = f2bf(v.w);
        *(ushort4*)(wkvb + idx) = o;
    } else if (blk < 384) {          // woutb: w_out -> bf16
        const int idx = ((blk - 256) * 256 + tid) * 4;
        float4 v = *(const float4*)(w_out + idx);
        ushort4 o;
        o.x = f2bf(v.x); o.y = f2bf(v.y); o.z = f2bf(v.z); o.w = f2bf(v.w);
        *(ushort4*)(woutb + idx) = o;
    } else {                         // wqT[c][j] = bf16(w_qkv[j][c]), j<512
        const int t = blk - 384;     // 32 tiles: 8 j-tiles x 4 c-tiles
        const int j0 = (t >> 2) * 64, c0 = (t & 3) * 64;
        const int r = tid >> 4, cc = (tid & 15) * 4;
        #pragma unroll
        for (int p = 0; p < 4; ++p) {
            float4 v = *(const float4*)(w_qkv + (j0 + r + p * 16) * 256 + c0 + cc);
            T[r + p * 16][cc + 0] = v.x; T[r + p * 16][cc + 1] = v.y;
            T[r + p * 16][cc + 2] = v.z; T[r + p * 16][cc + 3] = v.w;
        }
        __syncthreads();
        const int c = tid >> 2, jj = (tid & 3) * 16;
        #pragma unroll
        for (int g = 0; g < 4; ++g) {
            ushort4 o;
            o.x = f2bf(T[jj + g * 4 + 0][c]);
            o.y = f2bf(T[jj + g * 4 + 1][c]);
            o.z = f2bf(T[jj + g * 4 + 2][c]);
            o.w = f2bf(T[jj + g * 4 + 3][c]);
            *(ushort4*)(wqT + (c0 + c) * 512 + j0 + jj + g * 4) = o;
        }
    }
}

// ------------ k1p: kv[b][r][n] = sum_c wkvb[r][c]*xbT[b][n][c] -------------
// W-resident: rows rb*128 (64KB LDS), cols ns*512 (4 subtiles x 128).
// X dbuf 2x8KB, counted vmcnt(2); drain only at subtile epilogues.
// rb<4: K rows -> store exp(acc), accumulate rowsum. rb>=4: V rows plain.
__global__ __launch_bounds__(256) void k1p(
    const unsigned short* __restrict__ wkvb,
    const unsigned short* __restrict__ xbT,
    unsigned short* __restrict__ kv, float* __restrict__ rowsum)
{
    __shared__ unsigned short Wl[32768];      // 8 k-subtiles x (128x32), 64 KB
    __shared__ unsigned short Xs[2][4096];    // dbuf, 8 KB each
    const int tid  = threadIdx.x;
    const int w = tid >> 6, lane = tid & 63;
    const int quad = lane >> 4, l16 = lane & 15;
    const int wm = (w >> 1) * 64, wn = (w & 1) * 64;
    const int ns = blockIdx.x, rb = blockIdx.y, b = blockIdx.z;

    const unsigned short* Wg = wkvb + (size_t)(rb * 128) * 256;
    const unsigned short* Xb = xbT + (size_t)b * 1048576 + (size_t)ns * 131072;

    // chunk mapping with source-side XOR involution (verified r3-r5)
    const int c0 = w * 128 + lane, c1 = c0 + 64;
    const int r0 = c0 >> 2, s0 = ((c0 & 3) ^ ((r0 >> 1) & 3)) * 8;
    const int r1 = c1 >> 2, s1 = ((c1 & 3) ^ ((r1 >> 1) & 3)) * 8;
    const int ldsw = w * 1024;

    #pragma unroll
    for (int ks = 0; ks < 8; ++ks) {
        gl_lds16(Wg + (size_t)r0 * 256 + ks * 32 + s0, &Wl[ks * 4096 + ldsw]);
        gl_lds16(Wg + (size_t)r1 * 256 + ks * 32 + s1, &Wl[ks * 4096 + ldsw + 512]);
    }
    const unsigned short* gX0 = Xb + (size_t)r0 * 256 + s0;
    const unsigned short* gX1 = Xb + (size_t)r1 * 256 + s1;
#define STGX(T) do { \
        const int o_ = ((T) >> 3) * 32768 + ((T) & 7) * 32; \
        gl_lds16(gX0 + o_, &Xs[(T) & 1][ldsw]); \
        gl_lds16(gX1 + o_, &Xs[(T) & 1][ldsw + 512]); } while (0)
    STGX(0); STGX(1);
    asm volatile("s_waitcnt vmcnt(0)" ::: "memory");
    __builtin_amdgcn_sched_barrier(0);
    __builtin_amdgcn_s_barrier();
    __builtin_amdgcn_sched_barrier(0);

    float rsum[4][4] = {};
    f32x4 acc[4][4] = {};
    unsigned short* Cb = kv + (size_t)b * 4194304 + (size_t)(rb * 128) * 4096 + ns * 512;

    #pragma unroll 2
    for (int t = 0; t < 32; ++t) {
        const unsigned short* xs = Xs[t & 1];
        const unsigned short* wl = &Wl[(t & 7) * 4096];
        frag8 a[4], bb[4];
        #pragma unroll
        for (int tt = 0; tt < 4; ++tt) {
            const int rn = wn + tt * 16 + l16;
            bb[tt] = *(const frag8*)(xs + rn * 32 + ((quad ^ ((rn >> 1) & 3)) << 3));
        }
        #pragma unroll
        for (int tt = 0; tt < 4; ++tt) {
            const int ra = wm + tt * 16 + l16;
            a[tt] = *(const frag8*)(wl + ra * 32 + ((quad ^ ((ra >> 1) & 3)) << 3));
        }
        asm volatile("s_waitcnt lgkmcnt(0)" ::: "memory");
        __builtin_amdgcn_sched_barrier(0);
        __builtin_amdgcn_s_barrier();     // all waves consumed Xs[t&1]
        __builtin_amdgcn_sched_barrier(0);
        if (t + 2 < 32) STGX(t + 2);      // overwrite the buffer just consumed
        #pragma unroll
        for (int mt = 0; mt < 4; ++mt)
            #pragma unroll
            for (int nt = 0; nt < 4; ++nt)
                acc[mt][nt] = __builtin_amdgcn_mfma_f32_16x16x32_bf16(
                    a[mt], bb[nt], acc[mt][nt], 0, 0, 0);
        if ((t & 7) == 7) {
            // subtile epilogue: write kv tile; K rows get exp + rowsum
            unsigned short* C = Cb + (t >> 3) * 128;
            if (rb < 4) {
                #pragma unroll
                for (int mt = 0; mt < 4; ++mt) {
                    const int row = wm + mt * 16 + quad * 4;
                    #pragma unroll
                    for (int nt = 0; nt < 4; ++nt) {
                        const int col = wn + nt * 16 + l16;
                        #pragma unroll
                        for (int r = 0; r < 4; ++r) {
                            float e = __expf(acc[mt][nt][r]);
                            rsum[mt][r] += e;
                            C[(size_t)(row + r) * 4096 + col] = f2bf(e);
                        }
                    }
                }
            } else {
                #pragma unroll
                for (int mt = 0; mt < 4; ++mt) {
                    const int row = wm + mt * 16 + quad * 4;
                    #pragma unroll
                    for (int nt = 0; nt < 4; ++nt) {
                        const int col = wn + nt * 16 + l16;
                        #pragma unroll
                        for (int r = 0; r < 4; ++r)
                            C[(size_t)(row + r) * 4096 + col] = f2bf(acc[mt][nt][r]);
                    }
                }
            }
            #pragma unroll
            for (int mt = 0; mt < 4; ++mt)
                #pragma unroll
                for (int nt = 0; nt < 4; ++nt)
                    acc[mt][nt] = (f32x4){0.f, 0.f, 0.f, 0.f};
            asm volatile("s_waitcnt vmcnt(0)" ::: "memory");   // stores mixed in vmcnt
        } else if (t + 2 < 32) {
            asm volatile("s_waitcnt vmcnt(2)" ::: "memory");   // stage(t+1) done
        } else {
            asm volatile("s_waitcnt vmcnt(0)" ::: "memory");
        }
        __builtin_amdgcn_sched_barrier(0);
        __builtin_amdgcn_s_barrier();
        __builtin_amdgcn_sched_barrier(0);
    }
#undef STGX
    if (rb < 4) {
        float* rs = rowsum + b * 512 + rb * 128;
        #pragma unroll
        for (int mt = 0; mt < 4; ++mt) {
            const int row = wm + mt * 16 + quad * 4;
            #pragma unroll
            for (int r = 0; r < 4; ++r) {
                float v = rsum[mt][r];
                v += __shfl_xor(v, 1, 64);
                v += __shfl_xor(v, 2, 64);
                v += __shfl_xor(v, 4, 64);
                v += __shfl_xor(v, 8, 64);
                if (l16 == 0) atomicAdd(rs + row + r, v);
            }
        }
    }
}

// -------- MFMA gemm_bt: C[m][n] = sum_k A[m][k] * B[n][k]  (bf16 in) -------
// 128x128 tile, BK=32, 4 waves, dbuf 2-phase: stage t+2 during compute of t,
// counted vmcnt(4). Staging XOR involution swizzle (source + read side).
// MODE 0: C bf16, z-strided (k5). MODE 1: C f32 + bias[row] (k6).
// MODE 2: ctx atomics, k-slice = blockIdx.x*512 (k3). MODE 3: k4 M.
template<int MODE>
__global__ __launch_bounds__(256) void mfma_bt(
    const unsigned short* __restrict__ A0, int lda,
    const unsigned short* __restrict__ B0, int ldb,
    void* __restrict__ C0, int ldc,
    const float* __restrict__ bias, int Kp,
    unsigned long long sAz, unsigned long long sBz, unsigned long long sCz)
{
    __shared__ unsigned short As[2][4096];
    __shared__ unsigned short Bs[2][4096];
    const int tid  = threadIdx.x;
    const int w    = tid >> 6, lane = tid & 63;
    const int quad = lane >> 4, l16 = lane & 15;
    const int wm = (w >> 1) * 64, wn = (w & 1) * 64;
    const int z = blockIdx.z;

    const unsigned short* A;
    const unsigned short* B;
    int m0, n0, ks, NS;
    if constexpr (MODE == 2) {
        m0 = 0; n0 = 0;
        ks = blockIdx.x * 512; NS = 16;
        const unsigned long long off =
            ((unsigned long long)(z >> 2) * 1024ull + (unsigned long long)(z & 3) * 128ull) * 4096ull;
        A = A0 + off; B = B0 + off;
    } else if constexpr (MODE == 3) {
        m0 = blockIdx.y * 128; n0 = 0;
        ks = 0; NS = Kp >> 5;
        A = A0 + (unsigned long long)(z & 3) * 128ull + (unsigned long long)m0 * lda;
        B = B0 + (unsigned long long)z * 16384ull;
    } else {
        m0 = blockIdx.y * 128; n0 = blockIdx.x * 128;
        ks = 0; NS = Kp >> 5;
        A = A0 + sAz * z + (unsigned long long)m0 * lda;
        B = B0 + sBz * z + (unsigned long long)n0 * ldb;
    }

    const int c0 = w * 128 + lane, c1 = c0 + 64;
    const int r0 = c0 >> 2, s0 = ((c0 & 3) ^ ((r0 >> 1) & 3)) * 8;
    const int r1 = c1 >> 2, s1 = ((c1 & 3) ^ ((r1 >> 1) & 3)) * 8;
    const unsigned short* gA0 = A + (unsigned long long)r0 * lda + s0 + ks;
    const unsigned short* gA1 = A + (unsigned long long)r1 * lda + s1 + ks;
    const unsigned short* gB0 = B + (unsigned long long)r0 * ldb + s0 + ks;
    const unsigned short* gB1 = B + (unsigned long long)r1 * ldb + s1 + ks;
    const int ldsw = w * 1024;

#define STG(T) do { \
        const int kk_ = (T) * 32; \
        gl_lds16(gA0 + kk_, &As[(T) & 1][ldsw]); \
        gl_lds16(gA1 + kk_, &As[(T) & 1][ldsw + 512]); \
        gl_lds16(gB0 + kk_, &Bs[(T) & 1][ldsw]); \
        gl_lds16(gB1 + kk_, &Bs[(T) & 1][ldsw + 512]); } while (0)

    STG(0); STG(1);
    asm volatile("s_waitcnt vmcnt(0)" ::: "memory");
    __builtin_amdgcn_sched_barrier(0);
    __builtin_amdgcn_s_barrier();
    __builtin_amdgcn_sched_barrier(0);

    f32x4 acc[4][4] = {};

    for (int t = 0; t < NS; ++t) {
        const unsigned short* as = As[t & 1];
        const unsigned short* bs = Bs[t & 1];
        frag8 a[4], bb[4];
        #pragma unroll
        for (int tt = 0; tt < 4; ++tt) {
            const int ra = wm + tt * 16 + l16;
            const int rn = wn + tt * 16 + l16;
            a[tt]  = *(const frag8*)(as + ra * 32 + ((quad ^ ((ra >> 1) & 3)) << 3));
            bb[tt] = *(const frag8*)(bs + rn * 32 + ((quad ^ ((rn >> 1) & 3)) << 3));
        }
        asm volatile("s_waitcnt lgkmcnt(0)" ::: "memory");
        __builtin_amdgcn_sched_barrier(0);
        __builtin_amdgcn_s_barrier();
        __builtin_amdgcn_sched_barrier(0);
        if (t + 2 < NS) STG(t + 2);
        #pragma unroll
        for (int mt = 0; mt < 4; ++mt)
            #pragma unroll
            for (int nt = 0; nt < 4; ++nt)
                acc[mt][nt] = __builtin_amdgcn_mfma_f32_16x16x32_bf16(
                    a[mt], bb[nt], acc[mt][nt], 0, 0, 0);
        if (t + 2 < NS) {
            asm volatile("s_waitcnt vmcnt(4)" ::: "memory");
        } else {
            asm volatile("s_waitcnt vmcnt(0)" ::: "memory");
        }
        __builtin_amdgcn_sched_barrier(0);
        __builtin_amdgcn_s_barrier();
        __builtin_amdgcn_sched_barrier(0);
    }
#undef STG

    // epilogue: C/D mapping col = lane&15, row = quad*4 + reg  [m91-verified]
    if constexpr (MODE == 0 || MODE == 3) {
        unsigned short* C;
        if constexpr (MODE == 0)
            C = (unsigned short*)C0 + sCz * z + (unsigned long long)m0 * ldc + n0;
        else
            C = (unsigned short*)C0 + (unsigned long long)(z >> 2) * 131072ull
              + (unsigned long long)(z & 3) * 128ull + (unsigned long long)m0 * ldc;
        #pragma unroll
        for (int mt = 0; mt < 4; ++mt) {
            const int row = wm + mt * 16 + quad * 4;
            #pragma unroll
            for (int nt = 0; nt < 4; ++nt) {
                const int col = wn + nt * 16 + l16;
                #pragma unroll
                for (int r = 0; r < 4; ++r)
                    C[(unsigned long long)(row + r) * ldc + col] = f2bf(acc[mt][nt][r]);
            }
        }
    } else if constexpr (MODE == 1) {
        float* C = (float*)C0 + sCz * z + (unsigned long long)m0 * ldc + n0;
        const float* bp = bias + m0;
        #pragma unroll
        for (int mt = 0; mt < 4; ++mt) {
            const int row = wm + mt * 16 + quad * 4;
            #pragma unroll
            for (int nt = 0; nt < 4; ++nt) {
                const int col = wn + nt * 16 + l16;
                #pragma unroll
                for (int r = 0; r < 4; ++r)
                    C[(unsigned long long)(row + r) * ldc + col] = acc[mt][nt][r] + bp[row + r];
            }
        }
    } else {
        // MODE 2: atomic accumulate f32 into ctx[z] (8 k-slices add here)
        float* C = (float*)C0 + (unsigned long long)z * 16384ull;
        #pragma unroll
        for (int mt = 0; mt < 4; ++mt) {
            const int row = wm + mt * 16 + quad * 4;
            #pragma unroll
            for (int nt = 0; nt < 4; ++nt) {
                const int col = wn + nt * 16 + l16;
                #pragma unroll
                for (int r = 0; r < 4; ++r)
                    atomicAdd(C + (row + r) * 128 + col, acc[mt][nt][r]);
            }
        }
    }
}

// ---- k3_scale: ctxb[bh][d][e] = bf16( ctx[bh][d][e] / rowsum[bh*128+d] ) --
__global__ __launch_bounds__(256) void k3_scale(
    const float* __restrict__ ctx, const float* __restrict__ rowsum,
    unsigned short* __restrict__ ctxb)
{
    const int idx = (blockIdx.x * 256 + threadIdx.x) * 4;   // element index
    const float inv = 1.0f / rowsum[idx >> 7];              // row = bh*128+d
    float4 t = *(const float4*)(ctx + idx);
    ushort4 o;
    o.x = f2bf(t.x * inv); o.y = f2bf(t.y * inv);
    o.z = f2bf(t.z * inv); o.w = f2bf(t.w * inv);
    *(ushort4*)(ctxb + idx) = o;
}

extern "C" void kernel_launch(void* const* d_in, const int* in_sizes, int n_in,
                              void* d_out, int out_size, void* d_ws, size_t ws_size,
                              hipStream_t stream) {
    (void)in_sizes; (void)n_in; (void)out_size; (void)ws_size;
    const float* x     = (const float*)d_in[0];  // f32 [8,256,64,64]
    const float* w_qkv = (const float*)d_in[1];  // f32 [1536,256]
    const float* w_out = (const float*)d_in[2];  // f32 [256,512]
    const float* b_out = (const float*)d_in[3];  // f32 [256]
    float* out = (float*)d_out;                  // f32 [8,256,64,64]

    char* ws = (char*)d_ws;
    unsigned short* xbT    = (unsigned short*)ws;                 // 16,777,216
    unsigned short* wkvb   = (unsigned short*)(ws + 16777216);    //    524,288
    unsigned short* woutb  = (unsigned short*)(ws + 17301504);    //    262,144
    unsigned short* wqT    = (unsigned short*)(ws + 17563648);    //    262,144
    float*          ctx    = (float*)(ws + 17825792);             //  2,097,152
    float*          rowsum = (float*)(ws + 19922944);             //     16,384
    unsigned short* ctxb   = (unsigned short*)(ws + 19939328);    //  1,048,576
    unsigned short* Mb     = (unsigned short*)(ws + 20987904);    //  2,097,152
    unsigned short* Nb     = (unsigned short*)(ws + 23085056);    //  1,048,576
    unsigned short* kv     = (unsigned short*)(ws + 24133632);    // 67,108,864

    // zero atomic accumulators (ctx + rowsum, adjacent): 2,113,536 B
    hipMemsetAsync(ws + 17825792, 0, 2097152 + 16384, stream);

    k0_prep<<<dim3(2464), 256, 0, stream>>>(x, w_qkv, w_out, xbT, wkvb, woutb, wqT);
    // k1p: kv (exp'd K rows + V rows), W-resident pipelined
    k1p<<<dim3(8, 8, 8), 256, 0, stream>>>(wkvb, xbT, kv, rowsum);
    // k3: ctx[bh,d,e] += sum_{n in slice} expK[d,n]*V[e,n]  (atomic, 8 slices)
    mfma_bt<2><<<dim3(8, 1, 32), 256, 0, stream>>>(
        kv, 4096, kv + (size_t)512 * 4096, 4096, ctx, 128, nullptr, 0,
        0ull, 0ull, 0ull);
    k3_scale<<<dim3(512), 256, 0, stream>>>(ctx, rowsum, ctxb);
    // k4: Mb[b][o][h*128+d] = sum_e woutb[o][h*128+e] * ctxb[bh][d][e]
    mfma_bt<3><<<dim3(1, 2, 32), 256, 0, stream>>>(
        woutb, 512, ctxb, 128, Mb, 512, nullptr, 128,
        0ull, 0ull, 0ull);
    // k5: Nb[b][o][c] = sum_j Mb[b][o][j] * wqT[c][j]
    mfma_bt<0><<<dim3(2, 2, 8), 256, 0, stream>>>(
        Mb, 512, wqT, 512, Nb, 256, nullptr, 512,
        131072ull, 0ull, 65536ull);
    // k6: out[b,o,n] = sum_c Nb[b,o,c] * xbT[b,n,c] + b_out[o]
    mfma_bt<1><<<dim3(32, 2, 8), 256, 0, stream>>>(
        Nb, 256, xbT, 256, out, 4096, b_out, 256,
        65536ull, 1048576ull, 1048576ull);
}